// Round 1
// baseline (435.127 us; speedup 1.0000x reference)
//
#include <hip/hip_runtime.h>

typedef _Float16 half8 __attribute__((ext_vector_type(8)));
typedef _Float16 half4v __attribute__((ext_vector_type(4)));
typedef float floatx4 __attribute__((ext_vector_type(4)));

#define AS3 __attribute__((address_space(3)))
#define AS1 __attribute__((address_space(1)))

// ---------------- f32 -> f16 convert (vectorized, memory-bound) ----------------
__global__ __launch_bounds__(256) void cvt_f32_f16(const float* __restrict__ in,
                                                   _Float16* __restrict__ out, int n4) {
    int i = blockIdx.x * 256 + threadIdx.x;
    if (i >= n4) return;
    float4 v = ((const float4*)in)[i];
    half4v h = {(_Float16)v.x, (_Float16)v.y, (_Float16)v.z, (_Float16)v.w};
    ((half4v*)out)[i] = h;
}

// ---------------- m97-style TN GEMM: C[M,N] = A[M,K] * B[N,K]^T ----------------
// 128x128 tile, BK=32, 256 threads (2x2 waves, each 64x64 = 4x4 16x16 tiles).
// global_load_lds width-16 staging (wave-uniform base + lane*16, unpadded LDS).
__global__ __launch_bounds__(256) void gemm_tn(
    const _Float16* __restrict__ A, const _Float16* __restrict__ B,
    _Float16* __restrict__ Ch, float* __restrict__ Cf, const float* __restrict__ bias,
    int M, int Nn, int K)
{
    __shared__ _Float16 sA[128 * 32];
    __shared__ _Float16 sB[128 * 32];
    const int tid  = threadIdx.x;
    const int lane = tid & 63, wave = tid >> 6;
    const int quad = lane >> 4, l16 = lane & 15;
    const int wr = wave >> 1, wc = wave & 1;
    const long m0 = (long)blockIdx.x * 128, n0 = (long)blockIdx.y * 128;

    // staging: chunk ci = tid + 256*i ; 4 chunks of 8 f16 per row
    const int srow = tid >> 2;
    const int scol = (tid & 3) * 8;
    const _Float16* gA0 = A + (m0 + srow) * (long)K + scol;
    const _Float16* gA1 = A + (m0 + srow + 64) * (long)K + scol;
    const _Float16* gB0 = B + (n0 + srow) * (long)K + scol;
    const _Float16* gB1 = B + (n0 + srow + 64) * (long)K + scol;
    AS3 _Float16* sA3 = (AS3 _Float16*)sA;
    AS3 _Float16* sB3 = (AS3 _Float16*)sB;
    const int lo0 = tid * 8, lo1 = (tid + 256) * 8;

    floatx4 acc[4][4] = {};

    for (int k0 = 0; k0 < K; k0 += 32) {
        __syncthreads();
        __builtin_amdgcn_global_load_lds((const AS1 void*)(gA0 + k0), (AS3 void*)(sA3 + lo0), 16, 0, 0);
        __builtin_amdgcn_global_load_lds((const AS1 void*)(gA1 + k0), (AS3 void*)(sA3 + lo1), 16, 0, 0);
        __builtin_amdgcn_global_load_lds((const AS1 void*)(gB0 + k0), (AS3 void*)(sB3 + lo0), 16, 0, 0);
        __builtin_amdgcn_global_load_lds((const AS1 void*)(gB1 + k0), (AS3 void*)(sB3 + lo1), 16, 0, 0);
        __syncthreads();

        half8 af[4], bf[4];
#pragma unroll
        for (int t = 0; t < 4; t++)
            af[t] = *(const half8*)&sA[(wr * 64 + t * 16 + l16) * 32 + quad * 8];
#pragma unroll
        for (int t = 0; t < 4; t++)
            bf[t] = *(const half8*)&sB[(wc * 64 + t * 16 + l16) * 32 + quad * 8];
#pragma unroll
        for (int tm = 0; tm < 4; tm++)
#pragma unroll
            for (int tn = 0; tn < 4; tn++)
                acc[tm][tn] = __builtin_amdgcn_mfma_f32_16x16x32_f16(af[tm], bf[tn], acc[tm][tn], 0, 0, 0);
    }

    // epilogue: C/D layout col=lane&15, row=quad*4+reg (verified m89/m91)
#pragma unroll
    for (int tm = 0; tm < 4; tm++) {
        long row = m0 + wr * 64 + tm * 16 + quad * 4;
#pragma unroll
        for (int tn = 0; tn < 4; tn++) {
            long col = n0 + wc * 64 + tn * 16 + l16;
            float bv = bias ? bias[col] : 0.f;
#pragma unroll
            for (int r = 0; r < 4; r++) {
                float v = acc[tm][tn][r];
                if (Cf) Cf[(row + r) * Nn + col] = v + bv;
                else    Ch[(row + r) * Nn + col] = (_Float16)v;
            }
        }
    }
}

// ---------------- flash attention ----------------
// qkv: [B*N, 3072] f16, layout [.., 3, H, 64]. out: [B*N, 1024] f16 ([B,N,H,D]).
// grid (B*H=128, N/128=8), block 256. Each wave owns 32 Q rows.
#define FSCALE 0.125f
__global__ __launch_bounds__(256) void flash_attn(const _Float16* __restrict__ qkv,
                                                  _Float16* __restrict__ out)
{
    const int bh = blockIdx.x;
    const int b = bh >> 4, h = bh & 15;
    const int n0 = blockIdx.y * 128;
    const int tid = threadIdx.x;
    const int lane = tid & 63, wave = tid >> 6;
    const int quad = lane >> 4, l16 = lane & 15;

    __shared__ _Float16 sK[128 * 72];       // [krow][d], pad 72 (row stride 144B, 16B-aligned, 2-way banks)
    __shared__ _Float16 sV[64 * 136];       // transposed [d][krow], pad 136 (272B stride)
    __shared__ _Float16 sP[4][16 * 136];    // per-wave P round-trip, one 16-row tile at a time

    const _Float16* qb = qkv + ((long)(b * 1024 + n0)) * 3072 + h * 64;
    const _Float16* kb = qkv + ((long)(b * 1024)) * 3072 + 1024 + h * 64;
    const _Float16* vb = qkv + ((long)(b * 1024)) * 3072 + 2048 + h * 64;

    // Q A-fragments pinned in registers: A[m=l16][k=quad*8+j], k-step s covers k = s*32..s*32+31
    half8 qf[2][2];
#pragma unroll
    for (int t = 0; t < 2; t++)
#pragma unroll
        for (int s = 0; s < 2; s++)
            qf[t][s] = *(const half8*)(qb + (long)(wave * 32 + t * 16 + l16) * 3072 + s * 32 + quad * 8);

    float m_i[2][4], l_i[2][4];
    floatx4 o[2][4] = {};
#pragma unroll
    for (int t = 0; t < 2; t++)
#pragma unroll
        for (int r = 0; r < 4; r++) { m_i[t][r] = -1e30f; l_i[t][r] = 0.f; }

    for (int kt = 0; kt < 8; kt++) {
        const int kr0 = kt * 128;
        __syncthreads();
        // stage K (row-major, padded) and V (transposed) — manual, 4x 16B loads/thread each
#pragma unroll
        for (int i = 0; i < 4; i++) {
            int ci = tid + i * 256;
            int row = ci >> 3, c8 = (ci & 7) * 8;
            half8 kv = *(const half8*)(kb + (long)(kr0 + row) * 3072 + c8);
            *(half8*)&sK[row * 72 + c8] = kv;
            half8 vv = *(const half8*)(vb + (long)(kr0 + row) * 3072 + c8);
#pragma unroll
            for (int j = 0; j < 8; j++) sV[(c8 + j) * 136 + row] = vv[j];
        }
        __syncthreads();

        // S = Q Kt^T : B-frag lane n=l16 reads K[n][k] contiguous
        floatx4 sacc[2][8];
#pragma unroll
        for (int c = 0; c < 8; c++) {
            half8 kf0 = *(const half8*)&sK[(c * 16 + l16) * 72 + quad * 8];
            half8 kf1 = *(const half8*)&sK[(c * 16 + l16) * 72 + 32 + quad * 8];
#pragma unroll
            for (int t = 0; t < 2; t++) {
                floatx4 a = {0.f, 0.f, 0.f, 0.f};
                a = __builtin_amdgcn_mfma_f32_16x16x32_f16(qf[t][0], kf0, a, 0, 0, 0);
                a = __builtin_amdgcn_mfma_f32_16x16x32_f16(qf[t][1], kf1, a, 0, 0, 0);
                sacc[t][c] = a;
            }
        }

        // online softmax (C-layout rows quad*4+r; reduce across 16 lanes sharing quad)
        float al[2][4];
#pragma unroll
        for (int t = 0; t < 2; t++)
#pragma unroll
            for (int r = 0; r < 4; r++) {
                float mx = -1e30f;
#pragma unroll
                for (int c = 0; c < 8; c++) { sacc[t][c][r] *= FSCALE; mx = fmaxf(mx, sacc[t][c][r]); }
                mx = fmaxf(mx, __shfl_xor(mx, 1));
                mx = fmaxf(mx, __shfl_xor(mx, 2));
                mx = fmaxf(mx, __shfl_xor(mx, 4));
                mx = fmaxf(mx, __shfl_xor(mx, 8));
                float mn = fmaxf(m_i[t][r], mx);
                al[t][r] = __expf(m_i[t][r] - mn);
                m_i[t][r] = mn;
            }
        float rs[2][4] = {};
#pragma unroll
        for (int t = 0; t < 2; t++)
#pragma unroll
            for (int c = 0; c < 8; c++)
#pragma unroll
                for (int r = 0; r < 4; r++) {
                    float p = __expf(sacc[t][c][r] - m_i[t][r]);
                    sacc[t][c][r] = p;
                    rs[t][r] += p;
                }
#pragma unroll
        for (int t = 0; t < 2; t++)
#pragma unroll
            for (int r = 0; r < 4; r++) {
                float s = rs[t][r];
                s += __shfl_xor(s, 1); s += __shfl_xor(s, 2);
                s += __shfl_xor(s, 4); s += __shfl_xor(s, 8);
                l_i[t][r] = l_i[t][r] * al[t][r] + s;
            }
#pragma unroll
        for (int t = 0; t < 2; t++)
#pragma unroll
            for (int d = 0; d < 4; d++)
#pragma unroll
                for (int r = 0; r < 4; r++) o[t][d][r] *= al[t][r];

        // PV: P through per-wave LDS (C-layout -> A-layout), V B-frag from transposed sV
#pragma unroll
        for (int t = 0; t < 2; t++) {
#pragma unroll
            for (int c = 0; c < 8; c++)
#pragma unroll
                for (int r = 0; r < 4; r++)
                    sP[wave][(quad * 4 + r) * 136 + c * 16 + l16] = (_Float16)sacc[t][c][r];
#pragma unroll
            for (int kk = 0; kk < 4; kk++) {
                half8 pf = *(const half8*)&sP[wave][l16 * 136 + kk * 32 + quad * 8];
#pragma unroll
                for (int d = 0; d < 4; d++) {
                    half8 vf = *(const half8*)&sV[(d * 16 + l16) * 136 + kk * 32 + quad * 8];
                    o[t][d] = __builtin_amdgcn_mfma_f32_16x16x32_f16(pf, vf, o[t][d], 0, 0, 0);
                }
            }
        }
    }

    // epilogue: out[b, n, h, d]
#pragma unroll
    for (int t = 0; t < 2; t++)
#pragma unroll
        for (int r = 0; r < 4; r++) {
            float inv = 1.f / l_i[t][r];
            long row = (long)(b * 1024 + n0 + wave * 32 + t * 16 + quad * 4 + r);
#pragma unroll
            for (int d = 0; d < 4; d++)
                out[row * 1024 + h * 64 + d * 16 + l16] = (_Float16)(o[t][d][r] * inv);
        }
}

// ---------------- launch ----------------
extern "C" void kernel_launch(void* const* d_in, const int* in_sizes, int n_in,
                              void* d_out, int out_size, void* d_ws, size_t ws_size,
                              hipStream_t stream) {
    const float* x      = (const float*)d_in[0];
    const float* w_qkv  = (const float*)d_in[1];
    const float* w_proj = (const float*)d_in[2];
    const float* b_proj = (const float*)d_in[3];

    char* ws = (char*)d_ws;
    _Float16* qkvh   = (_Float16*)ws;                                   // 48 MB [8192][3072]
    _Float16* xh     = (_Float16*)(ws + 50331648);                      // 16 MB [8192][1024]
    _Float16* attnh  = xh;                                              // alias: x consumed by GEMM1
    _Float16* wqkvh  = (_Float16*)(ws + 50331648 + 16777216);           // 6 MB [3072][1024]
    _Float16* wprojh = (_Float16*)(ws + 50331648 + 16777216 + 6291456); // 2 MB [1024][1024]

    cvt_f32_f16<<<8192, 256, 0, stream>>>(x, xh, 8388608 / 4);
    cvt_f32_f16<<<3072, 256, 0, stream>>>(w_qkv, wqkvh, 3145728 / 4);
    cvt_f32_f16<<<1024, 256, 0, stream>>>(w_proj, wprojh, 1048576 / 4);

    gemm_tn<<<dim3(64, 24), 256, 0, stream>>>(xh, wqkvh, qkvh, nullptr, nullptr, 8192, 3072, 1024);
    flash_attn<<<dim3(128, 8), 256, 0, stream>>>(qkvh, attnh);
    gemm_tn<<<dim3(64, 8), 256, 0, stream>>>(attnh, wprojh, nullptr, (float*)d_out, b_proj, 8192, 1024, 1024);
}

// Round 2
// 275.067 us; speedup vs baseline: 1.5819x; 1.5819x over previous
//
#include <hip/hip_runtime.h>

typedef _Float16 half8 __attribute__((ext_vector_type(8)));
typedef _Float16 half4v __attribute__((ext_vector_type(4)));
typedef _Float16 half2v __attribute__((ext_vector_type(2)));
typedef float floatx4 __attribute__((ext_vector_type(4)));

#define AS3 __attribute__((address_space(3)))
#define AS1 __attribute__((address_space(1)))

// ---------------- f32 -> f16 convert (vectorized, memory-bound) ----------------
__global__ __launch_bounds__(256) void cvt_f32_f16(const float* __restrict__ in,
                                                   _Float16* __restrict__ out, int n4) {
    int i = blockIdx.x * 256 + threadIdx.x;
    if (i >= n4) return;
    float4 v = ((const float4*)in)[i];
    half4v h = {(_Float16)v.x, (_Float16)v.y, (_Float16)v.z, (_Float16)v.w};
    ((half4v*)out)[i] = h;
}

// ---------------- m97-style TN GEMM: C[M,N] = A[M,K] * B[N,K]^T ----------------
// 128x128 tile, BK=32, 256 threads (2x2 waves, each 64x64 = 4x4 16x16 tiles).
// Output can split column-wise into (Ch, Ch2) at `split` (block-uniform), or go
// to f32 Cf with bias.
__global__ __launch_bounds__(256) void gemm_tn(
    const _Float16* __restrict__ A, const _Float16* __restrict__ B,
    _Float16* __restrict__ Ch, int ldc, _Float16* __restrict__ Ch2, int ldc2, int split,
    float* __restrict__ Cf, const float* __restrict__ bias,
    int M, int Nn, int K)
{
    __shared__ _Float16 sA[128 * 32];
    __shared__ _Float16 sB[128 * 32];
    const int tid  = threadIdx.x;
    const int lane = tid & 63, wave = tid >> 6;
    const int quad = lane >> 4, l16 = lane & 15;
    const int wr = wave >> 1, wc = wave & 1;
    const long m0 = (long)blockIdx.x * 128, n0 = (long)blockIdx.y * 128;

    const int srow = tid >> 2;
    const int scol = (tid & 3) * 8;
    const _Float16* gA0 = A + (m0 + srow) * (long)K + scol;
    const _Float16* gA1 = A + (m0 + srow + 64) * (long)K + scol;
    const _Float16* gB0 = B + (n0 + srow) * (long)K + scol;
    const _Float16* gB1 = B + (n0 + srow + 64) * (long)K + scol;
    AS3 _Float16* sA3 = (AS3 _Float16*)sA;
    AS3 _Float16* sB3 = (AS3 _Float16*)sB;
    const int lo0 = tid * 8, lo1 = (tid + 256) * 8;

    floatx4 acc[4][4] = {};

    for (int k0 = 0; k0 < K; k0 += 32) {
        __syncthreads();
        __builtin_amdgcn_global_load_lds((const AS1 void*)(gA0 + k0), (AS3 void*)(sA3 + lo0), 16, 0, 0);
        __builtin_amdgcn_global_load_lds((const AS1 void*)(gA1 + k0), (AS3 void*)(sA3 + lo1), 16, 0, 0);
        __builtin_amdgcn_global_load_lds((const AS1 void*)(gB0 + k0), (AS3 void*)(sB3 + lo0), 16, 0, 0);
        __builtin_amdgcn_global_load_lds((const AS1 void*)(gB1 + k0), (AS3 void*)(sB3 + lo1), 16, 0, 0);
        __syncthreads();

        half8 af[4], bf[4];
#pragma unroll
        for (int t = 0; t < 4; t++)
            af[t] = *(const half8*)&sA[(wr * 64 + t * 16 + l16) * 32 + quad * 8];
#pragma unroll
        for (int t = 0; t < 4; t++)
            bf[t] = *(const half8*)&sB[(wc * 64 + t * 16 + l16) * 32 + quad * 8];
#pragma unroll
        for (int tm = 0; tm < 4; tm++)
#pragma unroll
            for (int tn = 0; tn < 4; tn++)
                acc[tm][tn] = __builtin_amdgcn_mfma_f32_16x16x32_f16(af[tm], bf[tn], acc[tm][tn], 0, 0, 0);
    }

    // epilogue: C/D layout col=lane&15, row=quad*4+reg (verified m89/m91)
    const bool useC2 = (Cf == nullptr) && (n0 >= split);
#pragma unroll
    for (int tm = 0; tm < 4; tm++) {
        long row = m0 + wr * 64 + tm * 16 + quad * 4;
#pragma unroll
        for (int tn = 0; tn < 4; tn++) {
            long col = n0 + wc * 64 + tn * 16 + l16;
            float bv = bias ? bias[col] : 0.f;
#pragma unroll
            for (int r = 0; r < 4; r++) {
                float v = acc[tm][tn][r];
                if (Cf)        Cf[(row + r) * (long)Nn + col] = v + bv;
                else if (useC2) Ch2[(row + r) * (long)ldc2 + (col - split)] = (_Float16)v;
                else           Ch[(row + r) * (long)ldc + col] = (_Float16)v;
            }
        }
    }
}

// ---------------- V transpose: vh [B*N][1024] -> vt [B*H][64][1024] ----------------
// coalesced u16 reads (64 lanes = 128B contiguous), 16B scattered writes (L2 merges)
__global__ __launch_bounds__(256) void transpose_v(const _Float16* __restrict__ vh,
                                                   _Float16* __restrict__ vt) {
    const int bh = blockIdx.x;          // b*16+h
    const int b = bh >> 4, h = bh & 15;
    const int n0 = blockIdx.y * 64;
    const int d = threadIdx.x & 63;
    const int ng = threadIdx.x >> 6;
#pragma unroll
    for (int i = 0; i < 2; i++) {
        int nb = (ng + 4 * i) * 8;
        half8 vv;
#pragma unroll
        for (int j = 0; j < 8; j++)
            vv[j] = vh[(long)(b * 1024 + n0 + nb + j) * 1024 + h * 64 + d];
        *(half8*)&vt[((long)(bh * 64 + d)) * 1024 + n0 + nb] = vv;
    }
}

// ---------------- flash attention (S^T orientation) ----------------
// qk: [B*N][2048] f16 (Q cols 0..1023, K cols 1024..2047, per-head h*64 slices)
// vt: [B*H][64][1024] f16 (V^T per head)
// out: [B*N][1024] f16
// grid (B*H=128, N/128=8), block 256. Each wave owns 32 q-rows; KT=64.
#define CSC 0.125f
__global__ __launch_bounds__(256, 4) void flash_attn(const _Float16* __restrict__ qk,
                                                     const _Float16* __restrict__ vt,
                                                     _Float16* __restrict__ out)
{
    const int bh = blockIdx.x, b = bh >> 4, h = bh & 15;
    const int n0 = blockIdx.y * 128;
    const int tid = threadIdx.x, lane = tid & 63, wave = tid >> 6;
    const int quad = lane >> 4, l16 = lane & 15;

    __shared__ _Float16 sK[64 * 72];        // [kr][d] pad 72
    __shared__ _Float16 sVT[64 * 72];       // [d][kr] pad 72
    __shared__ _Float16 sPT[4][32 * 72];    // per-wave P^T round-trip [q][kr], reused as sOut

    // persistent Q B-frags: B[n=q=l16][k=d], k-step s covers d = s*32..s*32+31
    half8 qf[2][2];
    const _Float16* qbase = qk + (long)(b * 1024 + n0 + wave * 32) * 2048 + h * 64;
#pragma unroll
    for (int t = 0; t < 2; t++)
#pragma unroll
        for (int s = 0; s < 2; s++)
            qf[t][s] = *(const half8*)(qbase + (long)(t * 16 + l16) * 2048 + s * 32 + quad * 8);

    const int srow = tid >> 3, scol8 = (tid & 7) * 8;
    const _Float16* kgb = qk + 1024 + h * 64 + scol8 + (long)(b * 1024 + srow) * 2048;
    const _Float16* vgb = vt + (long)(bh * 64 + srow) * 1024 + scol8;

    float m_[2] = {-1e30f, -1e30f}, l_[2] = {0.f, 0.f};
    floatx4 o[2][4] = {};

    for (int kt = 0; kt < 16; kt++) {
        const int kr0 = kt * 64;
        __syncthreads();
        // stage K [64 kr][64 d] and V^T [64 d][64 kr], all-vector, 2 chunks each
#pragma unroll
        for (int i = 0; i < 2; i++) {
            int r = srow + i * 32;
            *(half8*)&sK[r * 72 + scol8]  = *(const half8*)(kgb + (long)(kr0 + i * 32) * 2048);
            *(half8*)&sVT[r * 72 + scol8] = *(const half8*)(vgb + (long)(i * 32) * 1024 + kr0);
        }
        __syncthreads();

        // S^T = K Q^T: A=K (m=kr), B=Q (n=q). C-layout: kr=c*16+quad*4+r, q=t*16+l16
        floatx4 sacc[2][4] = {};
#pragma unroll
        for (int c = 0; c < 4; c++)
#pragma unroll
            for (int s = 0; s < 2; s++) {
                half8 kf = *(const half8*)&sK[(c * 16 + l16) * 72 + s * 32 + quad * 8];
                sacc[0][c] = __builtin_amdgcn_mfma_f32_16x16x32_f16(kf, qf[0][s], sacc[0][c], 0, 0, 0);
                sacc[1][c] = __builtin_amdgcn_mfma_f32_16x16x32_f16(kf, qf[1][s], sacc[1][c], 0, 0, 0);
            }

        // online softmax over kr: in-lane reduce (16 vals) + 2 shuffles (xor16, xor32)
#pragma unroll
        for (int t = 0; t < 2; t++) {
            float mx = -1e30f;
#pragma unroll
            for (int c = 0; c < 4; c++)
#pragma unroll
                for (int r = 0; r < 4; r++) {
                    float v = sacc[t][c][r] * CSC;
                    sacc[t][c][r] = v;
                    mx = fmaxf(mx, v);
                }
            mx = fmaxf(mx, __shfl_xor(mx, 16));
            mx = fmaxf(mx, __shfl_xor(mx, 32));
            float mn = fmaxf(m_[t], mx);
            float al = __expf(m_[t] - mn);
            m_[t] = mn;
            float rs = 0.f;
#pragma unroll
            for (int c = 0; c < 4; c++)
#pragma unroll
                for (int r = 0; r < 4; r++) {
                    float p = __expf(sacc[t][c][r] - mn);
                    sacc[t][c][r] = p;
                    rs += p;
                }
            rs += __shfl_xor(rs, 16);
            rs += __shfl_xor(rs, 32);
            l_[t] = l_[t] * al + rs;
#pragma unroll
            for (int dt = 0; dt < 4; dt++) o[t][dt] *= al;
            // pack P^T -> sPT[q][kr], packed b32 writes (2 per c-tile)
#pragma unroll
            for (int c = 0; c < 4; c++) {
                half2v p01 = {(_Float16)sacc[t][c][0], (_Float16)sacc[t][c][1]};
                half2v p23 = {(_Float16)sacc[t][c][2], (_Float16)sacc[t][c][3]};
                *(half2v*)&sPT[wave][(t * 16 + l16) * 72 + c * 16 + quad * 4]     = p01;
                *(half2v*)&sPT[wave][(t * 16 + l16) * 72 + c * 16 + quad * 4 + 2] = p23;
            }
        }

        // PV: O^T += V^T P^T. A = V^T (m=d), B = P (n=q) from sPT. Per-wave, in-order LDS.
#pragma unroll
        for (int kk = 0; kk < 2; kk++) {
            half8 pf0 = *(const half8*)&sPT[wave][(l16) * 72 + kk * 32 + quad * 8];
            half8 pf1 = *(const half8*)&sPT[wave][(16 + l16) * 72 + kk * 32 + quad * 8];
#pragma unroll
            for (int dt = 0; dt < 4; dt++) {
                half8 vf = *(const half8*)&sVT[(dt * 16 + l16) * 72 + kk * 32 + quad * 8];
                o[0][dt] = __builtin_amdgcn_mfma_f32_16x16x32_f16(vf, pf0, o[0][dt], 0, 0, 0);
                o[1][dt] = __builtin_amdgcn_mfma_f32_16x16x32_f16(vf, pf1, o[1][dt], 0, 0, 0);
            }
        }
    }

    // epilogue: normalize, per-wave LDS transpose (O^T -> O), coalesced 16B stores
#pragma unroll
    for (int t = 0; t < 2; t++) {
        float inv = 1.f / l_[t];
#pragma unroll
        for (int dt = 0; dt < 4; dt++) {
            floatx4 v = o[t][dt];
            half2v a = {(_Float16)(v[0] * inv), (_Float16)(v[1] * inv)};
            half2v c = {(_Float16)(v[2] * inv), (_Float16)(v[3] * inv)};
            *(half2v*)&sPT[wave][(t * 16 + l16) * 72 + dt * 16 + quad * 4]     = a;
            *(half2v*)&sPT[wave][(t * 16 + l16) * 72 + dt * 16 + quad * 4 + 2] = c;
        }
    }
    __syncthreads();
#pragma unroll
    for (int i = 0; i < 4; i++) {
        int ql = i * 8 + (lane >> 3);
        int c8 = (lane & 7) * 8;
        half8 vv = *(const half8*)&sPT[wave][ql * 72 + c8];
        *(half8*)(out + (long)(b * 1024 + n0 + wave * 32 + ql) * 1024 + h * 64 + c8) = vv;
    }
}

// ---------------- launch ----------------
extern "C" void kernel_launch(void* const* d_in, const int* in_sizes, int n_in,
                              void* d_out, int out_size, void* d_ws, size_t ws_size,
                              hipStream_t stream) {
    const float* x      = (const float*)d_in[0];
    const float* w_qkv  = (const float*)d_in[1];
    const float* w_proj = (const float*)d_in[2];
    const float* b_proj = (const float*)d_in[3];

    char* ws = (char*)d_ws;
    _Float16* qkh    = (_Float16*)ws;                      // 32MB [8192][2048] (Q|K)
    _Float16* vh     = (_Float16*)(ws + 33554432);         // 16MB [8192][1024] (V); attnh alias
    _Float16* xh     = (_Float16*)(ws + 50331648);         // 16MB [8192][1024]; vT alias
    _Float16* wqkvh  = (_Float16*)(ws + 67108864);         // 6MB [3072][1024]
    _Float16* wprojh = (_Float16*)(ws + 73400320);         // 2MB [1024][1024]
    _Float16* vT     = xh;                                 // [128][64][1024] after GEMM1
    _Float16* attnh  = vh;                                 // flash out, after transpose

    cvt_f32_f16<<<8192, 256, 0, stream>>>(x, xh, 8388608 / 4);
    cvt_f32_f16<<<3072, 256, 0, stream>>>(w_qkv, wqkvh, 3145728 / 4);
    cvt_f32_f16<<<1024, 256, 0, stream>>>(w_proj, wprojh, 1048576 / 4);

    // QKV GEMM: cols 0..2047 -> qkh, cols 2048..3071 -> vh
    gemm_tn<<<dim3(64, 24), 256, 0, stream>>>(xh, wqkvh, qkh, 2048, vh, 1024, 2048,
                                              nullptr, nullptr, 8192, 3072, 1024);
    transpose_v<<<dim3(128, 16), 256, 0, stream>>>(vh, vT);
    flash_attn<<<dim3(128, 8), 256, 0, stream>>>(qkh, vT, attnh);
    gemm_tn<<<dim3(64, 8), 256, 0, stream>>>(attnh, wprojh, nullptr, 0, nullptr, 0, 1 << 30,
                                             (float*)d_out, b_proj, 8192, 1024, 1024);
}

// Round 3
// 274.799 us; speedup vs baseline: 1.5834x; 1.0010x over previous
//
#include <hip/hip_runtime.h>

typedef _Float16 half8 __attribute__((ext_vector_type(8)));
typedef _Float16 half4v __attribute__((ext_vector_type(4)));
typedef _Float16 half2v __attribute__((ext_vector_type(2)));
typedef float floatx4 __attribute__((ext_vector_type(4)));

#define AS3 __attribute__((address_space(3)))
#define AS1 __attribute__((address_space(1)))

// ---------------- f32 -> f16 convert (vectorized, memory-bound) ----------------
__global__ __launch_bounds__(256) void cvt_f32_f16(const float* __restrict__ in,
                                                   _Float16* __restrict__ out, int n4) {
    int i = blockIdx.x * 256 + threadIdx.x;
    if (i >= n4) return;
    float4 v = ((const float4*)in)[i];
    half4v h = {(_Float16)v.x, (_Float16)v.y, (_Float16)v.z, (_Float16)v.w};
    ((half4v*)out)[i] = h;
}

// ---------------- TN GEMM with XOR-swizzled LDS: C[M,N] = A[M,K] * B[N,K]^T ----
// 128x128 tile, BK=32, 256 threads (2x2 waves, each 64x64 = 4x4 16x16 tiles).
// LDS placement: global 16B-chunk c of row r lives at slot c ^ ((r>>1)&3).
// Makes the MFMA fragment reads bank-uniform (8 lanes per 16B chunk-col = min).
__global__ __launch_bounds__(256) void gemm_tn(
    const _Float16* __restrict__ A, const _Float16* __restrict__ B,
    _Float16* __restrict__ Ch, int ldc, _Float16* __restrict__ Ch2, int ldc2, int split,
    float* __restrict__ Cf, const float* __restrict__ bias,
    int M, int Nn, int K)
{
    __shared__ _Float16 sA[128 * 32];
    __shared__ _Float16 sB[128 * 32];
    const int tid  = threadIdx.x;
    const int lane = tid & 63, wave = tid >> 6;
    const int quad = lane >> 4, l16 = lane & 15;
    const int wr = wave >> 1, wc = wave & 1;
    const long m0 = (long)blockIdx.x * 128, n0 = (long)blockIdx.y * 128;

    // staging: LDS slot = tid*8 f16 (and +2048 for rows 64..127). Source column
    // is swizzle-permuted within the 32-wide k-window (involution of placement).
    const int srow = tid >> 2;
    const int scol = (((tid & 3) ^ ((srow >> 1) & 3)) * 8);   // (srow+64)>>1 &3 == same
    const _Float16* gA0 = A + (m0 + srow) * (long)K + scol;
    const _Float16* gA1 = A + (m0 + srow + 64) * (long)K + scol;
    const _Float16* gB0 = B + (n0 + srow) * (long)K + scol;
    const _Float16* gB1 = B + (n0 + srow + 64) * (long)K + scol;
    AS3 _Float16* sA3 = (AS3 _Float16*)sA;
    AS3 _Float16* sB3 = (AS3 _Float16*)sB;
    const int lo0 = tid * 8, lo1 = (tid + 256) * 8;

    // fragment-read swizzle: row R = (t*16 + l16) (+64*wr) -> (R>>1)&3 == (l16>>1)&3
    const int swz = (l16 >> 1) & 3;
    const int aoff = ((quad ^ swz) * 8);

    floatx4 acc[4][4] = {};

    for (int k0 = 0; k0 < K; k0 += 32) {
        __syncthreads();
        __builtin_amdgcn_global_load_lds((const AS1 void*)(gA0 + k0), (AS3 void*)(sA3 + lo0), 16, 0, 0);
        __builtin_amdgcn_global_load_lds((const AS1 void*)(gA1 + k0), (AS3 void*)(sA3 + lo1), 16, 0, 0);
        __builtin_amdgcn_global_load_lds((const AS1 void*)(gB0 + k0), (AS3 void*)(sB3 + lo0), 16, 0, 0);
        __builtin_amdgcn_global_load_lds((const AS1 void*)(gB1 + k0), (AS3 void*)(sB3 + lo1), 16, 0, 0);
        __syncthreads();

        half8 af[4], bf[4];
#pragma unroll
        for (int t = 0; t < 4; t++)
            af[t] = *(const half8*)&sA[(wr * 64 + t * 16 + l16) * 32 + aoff];
#pragma unroll
        for (int t = 0; t < 4; t++)
            bf[t] = *(const half8*)&sB[(wc * 64 + t * 16 + l16) * 32 + aoff];
#pragma unroll
        for (int tm = 0; tm < 4; tm++)
#pragma unroll
            for (int tn = 0; tn < 4; tn++)
                acc[tm][tn] = __builtin_amdgcn_mfma_f32_16x16x32_f16(af[tm], bf[tn], acc[tm][tn], 0, 0, 0);
    }

    // epilogue: C/D layout col=lane&15, row=quad*4+reg (verified m89/m91)
    const bool useC2 = (Cf == nullptr) && (n0 >= split);
#pragma unroll
    for (int tm = 0; tm < 4; tm++) {
        long row = m0 + wr * 64 + tm * 16 + quad * 4;
#pragma unroll
        for (int tn = 0; tn < 4; tn++) {
            long col = n0 + wc * 64 + tn * 16 + l16;
            float bv = bias ? bias[col] : 0.f;
#pragma unroll
            for (int r = 0; r < 4; r++) {
                float v = acc[tm][tn][r];
                if (Cf)        Cf[(row + r) * (long)Nn + col] = v + bv;
                else if (useC2) Ch2[(row + r) * (long)ldc2 + (col - split)] = (_Float16)v;
                else           Ch[(row + r) * (long)ldc + col] = (_Float16)v;
            }
        }
    }
}

// ---------------- V transpose: vh [B*N][1024] -> vt [B*H][64][1024] ----------------
__global__ __launch_bounds__(256) void transpose_v(const _Float16* __restrict__ vh,
                                                   _Float16* __restrict__ vt) {
    const int bh = blockIdx.x;          // b*16+h
    const int b = bh >> 4, h = bh & 15;
    const int n0 = blockIdx.y * 64;
    const int d = threadIdx.x & 63;
    const int ng = threadIdx.x >> 6;
#pragma unroll
    for (int i = 0; i < 2; i++) {
        int nb = (ng + 4 * i) * 8;
        half8 vv;
#pragma unroll
        for (int j = 0; j < 8; j++)
            vv[j] = vh[(long)(b * 1024 + n0 + nb + j) * 1024 + h * 64 + d];
        *(half8*)&vt[((long)(bh * 64 + d)) * 1024 + n0 + nb] = vv;
    }
}

// ---------------- flash attention (S^T orientation) ----------------
#define CSC 0.125f
__global__ __launch_bounds__(256, 4) void flash_attn(const _Float16* __restrict__ qk,
                                                     const _Float16* __restrict__ vt,
                                                     _Float16* __restrict__ out)
{
    const int bh = blockIdx.x, b = bh >> 4, h = bh & 15;
    const int n0 = blockIdx.y * 128;
    const int tid = threadIdx.x, lane = tid & 63, wave = tid >> 6;
    const int quad = lane >> 4, l16 = lane & 15;

    __shared__ _Float16 sK[64 * 72];        // [kr][d] pad 72
    __shared__ _Float16 sVT[64 * 72];       // [d][kr] pad 72
    __shared__ _Float16 sPT[4][32 * 72];    // per-wave P^T round-trip [q][kr], reused as sOut

    half8 qf[2][2];
    const _Float16* qbase = qk + (long)(b * 1024 + n0 + wave * 32) * 2048 + h * 64;
#pragma unroll
    for (int t = 0; t < 2; t++)
#pragma unroll
        for (int s = 0; s < 2; s++)
            qf[t][s] = *(const half8*)(qbase + (long)(t * 16 + l16) * 2048 + s * 32 + quad * 8);

    const int srow = tid >> 3, scol8 = (tid & 7) * 8;
    const _Float16* kgb = qk + 1024 + h * 64 + scol8 + (long)(b * 1024 + srow) * 2048;
    const _Float16* vgb = vt + (long)(bh * 64 + srow) * 1024 + scol8;

    float m_[2] = {-1e30f, -1e30f}, l_[2] = {0.f, 0.f};
    floatx4 o[2][4] = {};

    for (int kt = 0; kt < 16; kt++) {
        const int kr0 = kt * 64;
        __syncthreads();
#pragma unroll
        for (int i = 0; i < 2; i++) {
            int r = srow + i * 32;
            *(half8*)&sK[r * 72 + scol8]  = *(const half8*)(kgb + (long)(kr0 + i * 32) * 2048);
            *(half8*)&sVT[r * 72 + scol8] = *(const half8*)(vgb + (long)(i * 32) * 1024 + kr0);
        }
        __syncthreads();

        // S^T = K Q^T: A=K (m=kr), B=Q (n=q). C-layout: kr=c*16+quad*4+r, q=t*16+l16
        floatx4 sacc[2][4] = {};
#pragma unroll
        for (int c = 0; c < 4; c++)
#pragma unroll
            for (int s = 0; s < 2; s++) {
                half8 kf = *(const half8*)&sK[(c * 16 + l16) * 72 + s * 32 + quad * 8];
                sacc[0][c] = __builtin_amdgcn_mfma_f32_16x16x32_f16(kf, qf[0][s], sacc[0][c], 0, 0, 0);
                sacc[1][c] = __builtin_amdgcn_mfma_f32_16x16x32_f16(kf, qf[1][s], sacc[1][c], 0, 0, 0);
            }

        // online softmax over kr: in-lane reduce + 2 shuffles (xor16, xor32)
#pragma unroll
        for (int t = 0; t < 2; t++) {
            float mx = -1e30f;
#pragma unroll
            for (int c = 0; c < 4; c++)
#pragma unroll
                for (int r = 0; r < 4; r++) {
                    float v = sacc[t][c][r] * CSC;
                    sacc[t][c][r] = v;
                    mx = fmaxf(mx, v);
                }
            mx = fmaxf(mx, __shfl_xor(mx, 16));
            mx = fmaxf(mx, __shfl_xor(mx, 32));
            float mn = fmaxf(m_[t], mx);
            float al = __expf(m_[t] - mn);
            m_[t] = mn;
            float rs = 0.f;
#pragma unroll
            for (int c = 0; c < 4; c++)
#pragma unroll
                for (int r = 0; r < 4; r++) {
                    float p = __expf(sacc[t][c][r] - mn);
                    sacc[t][c][r] = p;
                    rs += p;
                }
            rs += __shfl_xor(rs, 16);
            rs += __shfl_xor(rs, 32);
            l_[t] = l_[t] * al + rs;
#pragma unroll
            for (int dt = 0; dt < 4; dt++) o[t][dt] *= al;
#pragma unroll
            for (int c = 0; c < 4; c++) {
                half2v p01 = {(_Float16)sacc[t][c][0], (_Float16)sacc[t][c][1]};
                half2v p23 = {(_Float16)sacc[t][c][2], (_Float16)sacc[t][c][3]};
                *(half2v*)&sPT[wave][(t * 16 + l16) * 72 + c * 16 + quad * 4]     = p01;
                *(half2v*)&sPT[wave][(t * 16 + l16) * 72 + c * 16 + quad * 4 + 2] = p23;
            }
        }

        // PV: O^T += V^T P^T. A = V^T (m=d), B = P (n=q) from sPT.
#pragma unroll
        for (int kk = 0; kk < 2; kk++) {
            half8 pf0 = *(const half8*)&sPT[wave][(l16) * 72 + kk * 32 + quad * 8];
            half8 pf1 = *(const half8*)&sPT[wave][(16 + l16) * 72 + kk * 32 + quad * 8];
#pragma unroll
            for (int dt = 0; dt < 4; dt++) {
                half8 vf = *(const half8*)&sVT[(dt * 16 + l16) * 72 + kk * 32 + quad * 8];
                o[0][dt] = __builtin_amdgcn_mfma_f32_16x16x32_f16(vf, pf0, o[0][dt], 0, 0, 0);
                o[1][dt] = __builtin_amdgcn_mfma_f32_16x16x32_f16(vf, pf1, o[1][dt], 0, 0, 0);
            }
        }
    }

    // epilogue: normalize, per-wave LDS transpose (O^T -> O), coalesced 16B stores
#pragma unroll
    for (int t = 0; t < 2; t++) {
        float inv = 1.f / l_[t];
#pragma unroll
        for (int dt = 0; dt < 4; dt++) {
            floatx4 v = o[t][dt];
            half2v a = {(_Float16)(v[0] * inv), (_Float16)(v[1] * inv)};
            half2v c = {(_Float16)(v[2] * inv), (_Float16)(v[3] * inv)};
            *(half2v*)&sPT[wave][(t * 16 + l16) * 72 + dt * 16 + quad * 4]     = a;
            *(half2v*)&sPT[wave][(t * 16 + l16) * 72 + dt * 16 + quad * 4 + 2] = c;
        }
    }
    __syncthreads();
#pragma unroll
    for (int i = 0; i < 4; i++) {
        int ql = i * 8 + (lane >> 3);
        int c8 = (lane & 7) * 8;
        half8 vv = *(const half8*)&sPT[wave][ql * 72 + c8];
        *(half8*)(out + (long)(b * 1024 + n0 + wave * 32 + ql) * 1024 + h * 64 + c8) = vv;
    }
}

// ---------------- launch ----------------
extern "C" void kernel_launch(void* const* d_in, const int* in_sizes, int n_in,
                              void* d_out, int out_size, void* d_ws, size_t ws_size,
                              hipStream_t stream) {
    const float* x      = (const float*)d_in[0];
    const float* w_qkv  = (const float*)d_in[1];
    const float* w_proj = (const float*)d_in[2];
    const float* b_proj = (const float*)d_in[3];

    char* ws = (char*)d_ws;
    _Float16* qkh    = (_Float16*)ws;                      // 32MB [8192][2048] (Q|K)
    _Float16* vh     = (_Float16*)(ws + 33554432);         // 16MB [8192][1024] (V); attnh alias
    _Float16* xh     = (_Float16*)(ws + 50331648);         // 16MB [8192][1024]; vT alias
    _Float16* wqkvh  = (_Float16*)(ws + 67108864);         // 6MB [3072][1024]
    _Float16* wprojh = (_Float16*)(ws + 73400320);         // 2MB [1024][1024]
    _Float16* vT     = xh;                                 // [128][64][1024] after GEMM1
    _Float16* attnh  = vh;                                 // flash out, after transpose

    cvt_f32_f16<<<8192, 256, 0, stream>>>(x, xh, 8388608 / 4);
    cvt_f32_f16<<<3072, 256, 0, stream>>>(w_qkv, wqkvh, 3145728 / 4);
    cvt_f32_f16<<<1024, 256, 0, stream>>>(w_proj, wprojh, 1048576 / 4);

    // QKV GEMM: cols 0..2047 -> qkh, cols 2048..3071 -> vh
    gemm_tn<<<dim3(64, 24), 256, 0, stream>>>(xh, wqkvh, qkh, 2048, vh, 1024, 2048,
                                              nullptr, nullptr, 8192, 3072, 1024);
    transpose_v<<<dim3(128, 16), 256, 0, stream>>>(vh, vT);
    flash_attn<<<dim3(128, 8), 256, 0, stream>>>(qkh, vT, attnh);
    gemm_tn<<<dim3(64, 8), 256, 0, stream>>>(attnh, wprojh, nullptr, 0, nullptr, 0, 1 << 30,
                                             (float*)d_out, b_proj, 8192, 1024, 1024);
}

// Round 4
// 265.362 us; speedup vs baseline: 1.6397x; 1.0356x over previous
//
#include <hip/hip_runtime.h>

typedef _Float16 half8 __attribute__((ext_vector_type(8)));
typedef _Float16 half4v __attribute__((ext_vector_type(4)));
typedef _Float16 half2v __attribute__((ext_vector_type(2)));
typedef float floatx4 __attribute__((ext_vector_type(4)));

#define AS3 __attribute__((address_space(3)))
#define AS1 __attribute__((address_space(1)))

// ---------------- f32 -> f16 convert (vectorized, memory-bound) ----------------
__global__ __launch_bounds__(256) void cvt_f32_f16(const float* __restrict__ in,
                                                   _Float16* __restrict__ out, int n4) {
    int i = blockIdx.x * 256 + threadIdx.x;
    if (i >= n4) return;
    float4 v = ((const float4*)in)[i];
    half4v h = {(_Float16)v.x, (_Float16)v.y, (_Float16)v.z, (_Float16)v.w};
    ((half4v*)out)[i] = h;
}

// ---------------- TN GEMM, double-buffered LDS, XOR-swizzled ----------------
// C[M,N] = A[M,K] * B[N,K]^T. 128x128 tile, BK=32, 256 threads.
// ONE barrier per k-iter: stage(next buf) right after barrier, compute cur buf.
// vmcnt(0)-drain at the barrier then waits for loads issued a full compute
// phase ago (prefetch distance 1) instead of loads issued just before.
__global__ __launch_bounds__(256) void gemm_tn(
    const _Float16* __restrict__ A, const _Float16* __restrict__ B,
    _Float16* __restrict__ Ch, int ldc, _Float16* __restrict__ Ch2, int ldc2, int split,
    float* __restrict__ Cf, const float* __restrict__ bias,
    int M, int Nn, int K)
{
    __shared__ _Float16 sA[2][128 * 32];
    __shared__ _Float16 sB[2][128 * 32];
    const int tid  = threadIdx.x;
    const int lane = tid & 63, wave = tid >> 6;
    const int quad = lane >> 4, l16 = lane & 15;
    const int wr = wave >> 1, wc = wave & 1;
    const long m0 = (long)blockIdx.x * 128, n0 = (long)blockIdx.y * 128;

    // staging: LDS slot = tid*8 f16 (+2048 for rows 64..127); source column is
    // swizzle-permuted within the 32-wide k-window (involution): chunk c of row
    // r lives at slot c ^ ((r>>1)&3). Bank-uniform fragment reads (verified R3:
    // SQ_LDS_BANK_CONFLICT = 0).
    const int srow = tid >> 2;
    const int scol = (((tid & 3) ^ ((srow >> 1) & 3)) * 8);
    const _Float16* gA0 = A + (m0 + srow) * (long)K + scol;
    const _Float16* gA1 = A + (m0 + srow + 64) * (long)K + scol;
    const _Float16* gB0 = B + (n0 + srow) * (long)K + scol;
    const _Float16* gB1 = B + (n0 + srow + 64) * (long)K + scol;
    AS3 _Float16* sA3 = (AS3 _Float16*)&sA[0][0];
    AS3 _Float16* sB3 = (AS3 _Float16*)&sB[0][0];
    const int lo0 = tid * 8, lo1 = (tid + 256) * 8;

    const int swz = (l16 >> 1) & 3;
    const int aoff = ((quad ^ swz) * 8);

    floatx4 acc[4][4] = {};

    const int nk = K >> 5;
    // prologue: stage k-block 0 into buffer 0
    __builtin_amdgcn_global_load_lds((const AS1 void*)gA0, (AS3 void*)(sA3 + lo0), 16, 0, 0);
    __builtin_amdgcn_global_load_lds((const AS1 void*)gA1, (AS3 void*)(sA3 + lo1), 16, 0, 0);
    __builtin_amdgcn_global_load_lds((const AS1 void*)gB0, (AS3 void*)(sB3 + lo0), 16, 0, 0);
    __builtin_amdgcn_global_load_lds((const AS1 void*)gB1, (AS3 void*)(sB3 + lo1), 16, 0, 0);

    for (int kk = 0; kk < nk; kk++) {
        const int cur = kk & 1;
        __syncthreads();   // vmcnt(0): cur buffer ready; all waves done reading next buffer
        if (kk + 1 < nk) {
            const int nb = (cur ^ 1) * 4096;
            const long k0 = (long)(kk + 1) << 5;
            __builtin_amdgcn_global_load_lds((const AS1 void*)(gA0 + k0), (AS3 void*)(sA3 + nb + lo0), 16, 0, 0);
            __builtin_amdgcn_global_load_lds((const AS1 void*)(gA1 + k0), (AS3 void*)(sA3 + nb + lo1), 16, 0, 0);
            __builtin_amdgcn_global_load_lds((const AS1 void*)(gB0 + k0), (AS3 void*)(sB3 + nb + lo0), 16, 0, 0);
            __builtin_amdgcn_global_load_lds((const AS1 void*)(gB1 + k0), (AS3 void*)(sB3 + nb + lo1), 16, 0, 0);
        }
        const _Float16* cA = &sA[cur][0];
        const _Float16* cB = &sB[cur][0];

        half8 af[4], bf[4];
#pragma unroll
        for (int t = 0; t < 4; t++)
            af[t] = *(const half8*)&cA[(wr * 64 + t * 16 + l16) * 32 + aoff];
#pragma unroll
        for (int t = 0; t < 4; t++)
            bf[t] = *(const half8*)&cB[(wc * 64 + t * 16 + l16) * 32 + aoff];
#pragma unroll
        for (int tm = 0; tm < 4; tm++)
#pragma unroll
            for (int tn = 0; tn < 4; tn++)
                acc[tm][tn] = __builtin_amdgcn_mfma_f32_16x16x32_f16(af[tm], bf[tn], acc[tm][tn], 0, 0, 0);
    }

    // epilogue: C/D layout col=lane&15, row=quad*4+reg (verified m89/m91)
    const bool useC2 = (Cf == nullptr) && (n0 >= split);
#pragma unroll
    for (int tm = 0; tm < 4; tm++) {
        long row = m0 + wr * 64 + tm * 16 + quad * 4;
#pragma unroll
        for (int tn = 0; tn < 4; tn++) {
            long col = n0 + wc * 64 + tn * 16 + l16;
            float bv = bias ? bias[col] : 0.f;
#pragma unroll
            for (int r = 0; r < 4; r++) {
                float v = acc[tm][tn][r];
                if (Cf)        Cf[(row + r) * (long)Nn + col] = v + bv;
                else if (useC2) Ch2[(row + r) * (long)ldc2 + (col - split)] = (_Float16)v;
                else           Ch[(row + r) * (long)ldc + col] = (_Float16)v;
            }
        }
    }
}

// ---------------- V transpose: vh [B*N][1024] -> vt [B*H][64][1024] ----------------
__global__ __launch_bounds__(256) void transpose_v(const _Float16* __restrict__ vh,
                                                   _Float16* __restrict__ vt) {
    const int bh = blockIdx.x;          // b*16+h
    const int b = bh >> 4, h = bh & 15;
    const int n0 = blockIdx.y * 64;
    const int d = threadIdx.x & 63;
    const int ng = threadIdx.x >> 6;
#pragma unroll
    for (int i = 0; i < 2; i++) {
        int nb = (ng + 4 * i) * 8;
        half8 vv;
#pragma unroll
        for (int j = 0; j < 8; j++)
            vv[j] = vh[(long)(b * 1024 + n0 + nb + j) * 1024 + h * 64 + d];
        *(half8*)&vt[((long)(bh * 64 + d)) * 1024 + n0 + nb] = vv;
    }
}

// ---------------- flash attention (S^T orientation) ----------------
#define CSC 0.125f
__global__ __launch_bounds__(256, 4) void flash_attn(const _Float16* __restrict__ qk,
                                                     const _Float16* __restrict__ vt,
                                                     _Float16* __restrict__ out)
{
    const int bh = blockIdx.x, b = bh >> 4, h = bh & 15;
    const int n0 = blockIdx.y * 128;
    const int tid = threadIdx.x, lane = tid & 63, wave = tid >> 6;
    const int quad = lane >> 4, l16 = lane & 15;

    __shared__ _Float16 sK[64 * 72];        // [kr][d] pad 72
    __shared__ _Float16 sVT[64 * 72];       // [d][kr] pad 72
    __shared__ _Float16 sPT[4][32 * 72];    // per-wave P^T round-trip [q][kr], reused as sOut

    half8 qf[2][2];
    const _Float16* qbase = qk + (long)(b * 1024 + n0 + wave * 32) * 2048 + h * 64;
#pragma unroll
    for (int t = 0; t < 2; t++)
#pragma unroll
        for (int s = 0; s < 2; s++)
            qf[t][s] = *(const half8*)(qbase + (long)(t * 16 + l16) * 2048 + s * 32 + quad * 8);

    const int srow = tid >> 3, scol8 = (tid & 7) * 8;
    const _Float16* kgb = qk + 1024 + h * 64 + scol8 + (long)(b * 1024 + srow) * 2048;
    const _Float16* vgb = vt + (long)(bh * 64 + srow) * 1024 + scol8;

    float m_[2] = {-1e30f, -1e30f}, l_[2] = {0.f, 0.f};
    floatx4 o[2][4] = {};

    for (int kt = 0; kt < 16; kt++) {
        const int kr0 = kt * 64;
        __syncthreads();
#pragma unroll
        for (int i = 0; i < 2; i++) {
            int r = srow + i * 32;
            *(half8*)&sK[r * 72 + scol8]  = *(const half8*)(kgb + (long)(kr0 + i * 32) * 2048);
            *(half8*)&sVT[r * 72 + scol8] = *(const half8*)(vgb + (long)(i * 32) * 1024 + kr0);
        }
        __syncthreads();

        // S^T = K Q^T: A=K (m=kr), B=Q (n=q). C-layout: kr=c*16+quad*4+r, q=t*16+l16
        floatx4 sacc[2][4] = {};
#pragma unroll
        for (int c = 0; c < 4; c++)
#pragma unroll
            for (int s = 0; s < 2; s++) {
                half8 kf = *(const half8*)&sK[(c * 16 + l16) * 72 + s * 32 + quad * 8];
                sacc[0][c] = __builtin_amdgcn_mfma_f32_16x16x32_f16(kf, qf[0][s], sacc[0][c], 0, 0, 0);
                sacc[1][c] = __builtin_amdgcn_mfma_f32_16x16x32_f16(kf, qf[1][s], sacc[1][c], 0, 0, 0);
            }

        // online softmax over kr: in-lane reduce + 2 shuffles (xor16, xor32)
#pragma unroll
        for (int t = 0; t < 2; t++) {
            float mx = -1e30f;
#pragma unroll
            for (int c = 0; c < 4; c++)
#pragma unroll
                for (int r = 0; r < 4; r++) {
                    float v = sacc[t][c][r] * CSC;
                    sacc[t][c][r] = v;
                    mx = fmaxf(mx, v);
                }
            mx = fmaxf(mx, __shfl_xor(mx, 16));
            mx = fmaxf(mx, __shfl_xor(mx, 32));
            float mn = fmaxf(m_[t], mx);
            float al = __expf(m_[t] - mn);
            m_[t] = mn;
            float rs = 0.f;
#pragma unroll
            for (int c = 0; c < 4; c++)
#pragma unroll
                for (int r = 0; r < 4; r++) {
                    float p = __expf(sacc[t][c][r] - mn);
                    sacc[t][c][r] = p;
                    rs += p;
                }
            rs += __shfl_xor(rs, 16);
            rs += __shfl_xor(rs, 32);
            l_[t] = l_[t] * al + rs;
#pragma unroll
            for (int dt = 0; dt < 4; dt++) o[t][dt] *= al;
#pragma unroll
            for (int c = 0; c < 4; c++) {
                half2v p01 = {(_Float16)sacc[t][c][0], (_Float16)sacc[t][c][1]};
                half2v p23 = {(_Float16)sacc[t][c][2], (_Float16)sacc[t][c][3]};
                *(half2v*)&sPT[wave][(t * 16 + l16) * 72 + c * 16 + quad * 4]     = p01;
                *(half2v*)&sPT[wave][(t * 16 + l16) * 72 + c * 16 + quad * 4 + 2] = p23;
            }
        }

        // PV: O^T += V^T P^T. A = V^T (m=d), B = P (n=q) from sPT.
#pragma unroll
        for (int kk = 0; kk < 2; kk++) {
            half8 pf0 = *(const half8*)&sPT[wave][(l16) * 72 + kk * 32 + quad * 8];
            half8 pf1 = *(const half8*)&sPT[wave][(16 + l16) * 72 + kk * 32 + quad * 8];
#pragma unroll
            for (int dt = 0; dt < 4; dt++) {
                half8 vf = *(const half8*)&sVT[(dt * 16 + l16) * 72 + kk * 32 + quad * 8];
                o[0][dt] = __builtin_amdgcn_mfma_f32_16x16x32_f16(vf, pf0, o[0][dt], 0, 0, 0);
                o[1][dt] = __builtin_amdgcn_mfma_f32_16x16x32_f16(vf, pf1, o[1][dt], 0, 0, 0);
            }
        }
    }

    // epilogue: normalize, per-wave LDS transpose (O^T -> O), coalesced 16B stores
#pragma unroll
    for (int t = 0; t < 2; t++) {
        float inv = 1.f / l_[t];
#pragma unroll
        for (int dt = 0; dt < 4; dt++) {
            floatx4 v = o[t][dt];
            half2v a = {(_Float16)(v[0] * inv), (_Float16)(v[1] * inv)};
            half2v c = {(_Float16)(v[2] * inv), (_Float16)(v[3] * inv)};
            *(half2v*)&sPT[wave][(t * 16 + l16) * 72 + dt * 16 + quad * 4]     = a;
            *(half2v*)&sPT[wave][(t * 16 + l16) * 72 + dt * 16 + quad * 4 + 2] = c;
        }
    }
    __syncthreads();
#pragma unroll
    for (int i = 0; i < 4; i++) {
        int ql = i * 8 + (lane >> 3);
        int c8 = (lane & 7) * 8;
        half8 vv = *(const half8*)&sPT[wave][ql * 72 + c8];
        *(half8*)(out + (long)(b * 1024 + n0 + wave * 32 + ql) * 1024 + h * 64 + c8) = vv;
    }
}

// ---------------- launch ----------------
extern "C" void kernel_launch(void* const* d_in, const int* in_sizes, int n_in,
                              void* d_out, int out_size, void* d_ws, size_t ws_size,
                              hipStream_t stream) {
    const float* x      = (const float*)d_in[0];
    const float* w_qkv  = (const float*)d_in[1];
    const float* w_proj = (const float*)d_in[2];
    const float* b_proj = (const float*)d_in[3];

    char* ws = (char*)d_ws;
    _Float16* qkh    = (_Float16*)ws;                      // 32MB [8192][2048] (Q|K)
    _Float16* vh     = (_Float16*)(ws + 33554432);         // 16MB [8192][1024] (V); attnh alias
    _Float16* xh     = (_Float16*)(ws + 50331648);         // 16MB [8192][1024]; vT alias
    _Float16* wqkvh  = (_Float16*)(ws + 67108864);         // 6MB [3072][1024]
    _Float16* wprojh = (_Float16*)(ws + 73400320);         // 2MB [1024][1024]
    _Float16* vT     = xh;                                 // [128][64][1024] after GEMM1
    _Float16* attnh  = vh;                                 // flash out, after transpose

    cvt_f32_f16<<<8192, 256, 0, stream>>>(x, xh, 8388608 / 4);
    cvt_f32_f16<<<3072, 256, 0, stream>>>(w_qkv, wqkvh, 3145728 / 4);
    cvt_f32_f16<<<1024, 256, 0, stream>>>(w_proj, wprojh, 1048576 / 4);

    // QKV GEMM: cols 0..2047 -> qkh, cols 2048..3071 -> vh
    gemm_tn<<<dim3(64, 24), 256, 0, stream>>>(xh, wqkvh, qkh, 2048, vh, 1024, 2048,
                                              nullptr, nullptr, 8192, 3072, 1024);
    transpose_v<<<dim3(128, 16), 256, 0, stream>>>(vh, vT);
    flash_attn<<<dim3(128, 8), 256, 0, stream>>>(qkh, vT, attnh);
    gemm_tn<<<dim3(64, 8), 256, 0, stream>>>(attnh, wprojh, nullptr, 0, nullptr, 0, 1 << 30,
                                             (float*)d_out, b_proj, 8192, 1024, 1024);
}